// Round 1
// baseline (614.196 us; speedup 1.0000x reference)
//
#include <hip/hip_runtime.h>

// MergedEmbeddingBag forward: sum-pool, T tables merged.
// weights: [T, N, D] f32, indices: [T, TOTAL] i32, offsets: [T, B] i32
// out: [T, B, D] f32
//
// Structure: ONE BAG PER WAVE, float2 per lane (64 lanes x 8B = 512B = one row).
//  - bag id + all 20 indices are wave-uniform -> readfirstlane forces them to
//    SGPRs: index loads scalarize (s_load / K$), gather addresses become
//    SGPR-base + shared lane*8 voffset. VGPR use drops ~160 -> ~50, so
//    occupancy goes to ~8 waves/SIMD and wave count doubles vs the float4
//    version -> ~4x outstanding gathers to hide L3/HBM latency.
//  - output is write-once, never read -> nontemporal store keeps 64MB of
//    streaming writes from evicting weight rows out of L2/L3.
#define T_TABLES 8
#define N_ROWS   100000
#define DIM      128
#define BAGS     16384
#define BAG_L    20
#define TOTAL_IDX (BAGS * BAG_L)

#define DV2 (DIM / 2)   // float2 chunks per row = 64

typedef float v2f __attribute__((ext_vector_type(2)));

__global__ __launch_bounds__(256) void merged_embbag_kernel(
    const float2* __restrict__ weights,
    const int*    __restrict__ indices,
    const int*    __restrict__ offsets,
    float2*       __restrict__ out)
{
    const int lane = threadIdx.x & 63;

    // wave-uniform bag id, forced into SGPR so downstream uniform loads
    // (offsets, indices) can scalarize.
    const int wid = __builtin_amdgcn_readfirstlane(
        (int)(blockIdx.x * 4 + (threadIdx.x >> 6)));   // [0, T*B)
    const int b = wid & (BAGS - 1);
    const int t = wid >> 14;                           // BAGS == 2^14

    const int* off = offsets + t * BAGS;
    const int start = __builtin_amdgcn_readfirstlane(off[b]);
    const int end   = (b == BAGS - 1)
                        ? TOTAL_IDX
                        : __builtin_amdgcn_readfirstlane(off[b + 1]);
    const int n = end - start;

    const int*    idx   = indices + (size_t)t * TOTAL_IDX + start;
    const float2* wbase = weights + (size_t)t * N_ROWS * DV2;

    float2 acc = make_float2(0.f, 0.f);

    if (__builtin_expect(n == BAG_L, 1)) {
        // All rows to SGPRs up front (scalar loads, uniform address).
        int rows[BAG_L];
        #pragma unroll
        for (int j = 0; j < BAG_L; ++j)
            rows[j] = __builtin_amdgcn_readfirstlane(idx[j]);

        // 20 independent gathers in flight: SGPR row base + lane*8 voffset.
        float2 v[BAG_L];
        #pragma unroll
        for (int j = 0; j < BAG_L; ++j)
            v[j] = wbase[(size_t)rows[j] * DV2 + lane];

        #pragma unroll
        for (int j = 0; j < BAG_L; ++j) { acc.x += v[j].x; acc.y += v[j].y; }
    } else {
        // General fallback: arbitrary bag sizes (EmbeddingBag semantics).
        for (int p = 0; p < n; ++p) {
            int row = __builtin_amdgcn_readfirstlane(idx[p]);
            float2 v = wbase[(size_t)row * DV2 + lane];
            acc.x += v.x; acc.y += v.y;
        }
    }

    // Write-once output: nontemporal so it doesn't evict weight rows.
    v2f val; val.x = acc.x; val.y = acc.y;
    __builtin_nontemporal_store(val, (v2f*)(out + (size_t)wid * DV2 + lane));
}

extern "C" void kernel_launch(void* const* d_in, const int* in_sizes, int n_in,
                              void* d_out, int out_size, void* d_ws, size_t ws_size,
                              hipStream_t stream) {
    const float2* weights = (const float2*)d_in[0];
    const int*    indices = (const int*)d_in[1];
    const int*    offsets = (const int*)d_in[2];
    float2*       out     = (float2*)d_out;

    // one bag per wave, 4 waves (4 bags) per 256-thread block
    const int total_waves = T_TABLES * BAGS;          // 131072 bags
    const int block = 256;
    const int grid  = total_waves / 4;                // 32768 blocks
    merged_embbag_kernel<<<grid, block, 0, stream>>>(weights, indices, offsets, out);
}